// Round 9
// baseline (545.861 us; speedup 1.0000x reference)
//
#include <hip/hip_runtime.h>
#include <math.h>

// ---------------- Workspace layout ----------------
// floats:   [0, 40960)        td accumulator (4096 x 10)
//           [40960, 81920)    Wtdr[tt][j][row][k] reordered W_td
// bytes:    [524288, +166*8192)  Bg: bf16 hi/lo B slabs in MFMA-fragment
//           order, Bg[s][plane][n][16k]; slab 8192 B; 162 real + pad slabs
#define TD_OFF 0
#define WTDR_OFF 40960
#define BG_BYTE_OFF 524288

typedef __bf16 bf16x8 __attribute__((ext_vector_type(8)));
typedef float f32x16 __attribute__((ext_vector_type(16)));

union FragU { bf16x8 v; float4 f; };

__device__ __forceinline__ f32x16 mfma16(bf16x8 a, bf16x8 b, f32x16 c) {
    return __builtin_amdgcn_mfma_f32_32x32x16_bf16(a, b, c, 0, 0, 0);
}

__device__ __forceinline__ float eluf(float v) {
    return v > 0.f ? v : __expf(v) - 1.f;
}

// ---------------- prep: Wtdr reorder + Bg build ----------------------------
// Wtdr layout [tt][j][row][k]: lanes (row) read contiguous 512 B per (tt,j).
__global__ __launch_bounds__(256) void prep(const float* __restrict__ dw,
                                            const float* __restrict__ pw,
                                            const float* __restrict__ Wtd,
                                            float* __restrict__ Wtdr,
                                            unsigned short* __restrict__ Bg) {
    int gid = blockIdx.x * 256 + threadIdx.x;
    if (gid < 40960) {
        int k = gid & 3;
        int r = gid >> 2;
        int row = r & 31; r >>= 5;
        int j = r % 10;
        int tt = r / 10;
        Wtdr[gid] = Wtd[(size_t)(row * 128 + tt * 4 + k) * 10 + j];
        return;
    }
    int g2 = gid - 40960;
    if (g2 >= 162 * 128) return;
    int n = g2 & 127;
    int s = g2 >> 7;
    int half = s & 1;
    int cd = s >> 1;
    int c = cd / 27, d = cd % 27;
    int w = n >> 2, f = n & 3;
    unsigned short* dsth = Bg + (size_t)s * 4096 + n * 16;   // ushort units
    unsigned short* dstl = dsth + 2048;
#pragma unroll
    for (int k = 0; k < 16; k++) {
        int xi = half * 16 + k;
        int dx = xi - w + 13;
        float v = 0.f;
        if (dx >= 0 && dx < 27) {
#pragma unroll
            for (int m = 0; m < 5; m++)
                v = fmaf(dw[((d * 27 + dx) * 3 + c) * 5 + m],
                         pw[(c * 5 + m) * 4 + f], v);
        }
        __bf16 h = (__bf16)v;
        __bf16 l = (__bf16)(v - (float)h);
        dsth[k] = __builtin_bit_cast(unsigned short, h);
        dstl[k] = __builtin_bit_cast(unsigned short, l);
    }
}

// ---------------- LSTM branch: chunked-LDS x staging, W/U in registers -----
// 256 threads = 256 sequences/block. Wtdr reads now lane-contiguous.
__global__ void lstm_td(const float* __restrict__ x,
                        const float* __restrict__ W,
                        const float* __restrict__ U,
                        const float* __restrict__ Wtdr,
                        float* __restrict__ td_out) {
    __shared__ float xs[256 * 25];
    int t = threadIdx.x;

    float rW[48], rU[64];
    const float4* W4 = (const float4*)W;
    const float4* U4 = (const float4*)U;
#pragma unroll
    for (int i = 0; i < 12; i++) {
        float4 q = W4[i];
        rW[i * 4 + 0] = q.x; rW[i * 4 + 1] = q.y;
        rW[i * 4 + 2] = q.z; rW[i * 4 + 3] = q.w;
    }
#pragma unroll
    for (int i = 0; i < 16; i++) {
        float4 q = U4[i];
        rU[i * 4 + 0] = q.x; rU[i * 4 + 1] = q.y;
        rU[i * 4 + 2] = q.z; rU[i * 4 + 3] = q.w;
    }

    int n = blockIdx.x * 256 + t;   // n = b*32 + row
    int row = n & 31;
    const float4* xb4 = (const float4*)(x + (size_t)blockIdx.x * 24576);

    float h0 = 0, h1 = 0, h2 = 0, h3 = 0;
    float c0 = 0, c1 = 0, c2 = 0, c3 = 0;
    float acc[10];
#pragma unroll
    for (int j = 0; j < 10; j++) acc[j] = 0.f;

    for (int c4 = 0; c4 < 4; c4++) {
        __syncthreads();   // prior chunk's reads complete before overwrite
#pragma unroll
        for (int it = 0; it < 6; it++) {
            int fi = it * 256 + t;
            int s = fi / 6, e = fi - s * 6;
            float4 q = xb4[s * 24 + c4 * 6 + e];
            int base = s * 25 + e * 4;
            xs[base + 0] = q.x; xs[base + 1] = q.y;
            xs[base + 2] = q.z; xs[base + 3] = q.w;
        }
        __syncthreads();

#pragma unroll
        for (int st = 0; st < 8; st++) {
            int tt = c4 * 8 + st;
            float x0 = xs[t * 25 + st * 3 + 0];
            float x1 = xs[t * 25 + st * 3 + 1];
            float x2 = xs[t * 25 + st * 3 + 2];
            float z[16];
#pragma unroll
            for (int k = 0; k < 16; k++)
                z[k] = x0 * rW[k] + x1 * rW[16 + k] + x2 * rW[32 + k]
                     + h0 * rU[k] + h1 * rU[16 + k] + h2 * rU[32 + k] + h3 * rU[48 + k];

            float ig0 = eluf(z[0]),  ig1 = eluf(z[1]),  ig2 = eluf(z[2]),  ig3 = eluf(z[3]);
            float fg0 = eluf(z[4]),  fg1 = eluf(z[5]),  fg2 = eluf(z[6]),  fg3 = eluf(z[7]);
            float og0 = eluf(z[12]), og1 = eluf(z[13]), og2 = eluf(z[14]), og3 = eluf(z[15]);

            float zm = fmaxf(fmaxf(z[8], z[9]), fmaxf(z[10], z[11]));
            float e0 = __expf(z[8] - zm), e1 = __expf(z[9] - zm);
            float e2 = __expf(z[10] - zm), e3 = __expf(z[11] - zm);
            float inv = 1.f / (e0 + e1 + e2 + e3);
            c0 = fg0 * c0 + ig0 * (e0 * inv);
            c1 = fg1 * c1 + ig1 * (e1 * inv);
            c2 = fg2 * c2 + ig2 * (e2 * inv);
            c3 = fg3 * c3 + ig3 * (e3 * inv);

            float cm = fmaxf(fmaxf(c0, c1), fmaxf(c2, c3));
            float p0 = __expf(c0 - cm), p1 = __expf(c1 - cm);
            float p2 = __expf(c2 - cm), p3 = __expf(c3 - cm);
            float pinv = 1.f / (p0 + p1 + p2 + p3);
            h0 = og0 * (p0 * pinv); h1 = og1 * (p1 * pinv);
            h2 = og2 * (p2 * pinv); h3 = og3 * (p3 * pinv);

            // Wtdr[tt][j][row][k]: lane-contiguous float4 per (tt,j)
            const float4* wr4 = (const float4*)(Wtdr + (size_t)tt * 1280) + row;
#pragma unroll
            for (int j = 0; j < 10; j++) {
                float4 q = wr4[j * 32];
                acc[j] += h0 * q.x + h1 * q.y + h2 * q.z + h3 * q.w;
            }
        }
    }

#pragma unroll
    for (int off = 16; off >= 1; off >>= 1) {
#pragma unroll
        for (int j = 0; j < 10; j++) acc[j] += __shfl_xor(acc[j], off, 64);
    }
    int lane = t & 63;
    if (lane == 0 || lane == 32) {
        int b = n >> 5;
#pragma unroll
        for (int j = 0; j < 10; j++) td_out[b * 10 + j] = acc[j];
    }
}

// ---------------- conv branch: R5 geometry, 2 passes/block (no tail) -------
// Grid 1024 = exactly 4 blocks/CU resident (LDS 24.9KB, 6-capacity) -> one
// clean round. Each block processes image pairs bid*2 and bid*2+1.
#define A_OFF 0
#define ZOFF 24576           /* 16 B zeros */
#define SRED_OFF 24592       /* 4 waves * 2 img * 10 floats */
#define LDS_BYTES 24912

__global__ __launch_bounds__(256, 4) void conv_sc(const float* __restrict__ x,
                                                  const unsigned short* __restrict__ Bg,
                                                  const float* __restrict__ Wsc,
                                                  const float* __restrict__ bias,
                                                  const float* __restrict__ td,
                                                  float* __restrict__ out) {
    __shared__ char LDS[LDS_BYTES] __attribute__((aligned(16)));
    int t = threadIdx.x;
    int l = t & 63;
    int wv = t >> 6;          // ntile = wv
    int m = l & 31;
    int sub = l >> 5;         // k-subgroup (8 k's each)

    const char* bbase = (const char*)Bg + (size_t)wv * 1024 + m * 32 + sub * 16;
    FragU bufA[2], bufB[2], bufC[2];
#define LOADB(sv, arr) { const char* p_ = bbase + (size_t)(sv) * 8192;       \
        arr[0].f = *(const float4*)(p_);                                     \
        arr[1].f = *(const float4*)(p_ + 4096); }

    for (int pass = 0; pass < 2; pass++) {
        int bid = blockIdx.x * 2 + pass;
        if (pass) __syncthreads();   // epilogue reads done before A restage

        LOADB(0, bufA);
        LOADB(1, bufB);

        // ---- stage A: 2 images -> [img][c][oct(4hi,4lo)][row][16B] ----
        const float4* xb4 = (const float4*)(x + (size_t)bid * 6144);
#pragma unroll
        for (int it = 0; it < 6; it++) {
            int fi = it * 256 + t;            // 1536 float4 per pass
            float4 q = xb4[fi];
            float vals[4] = {q.x, q.y, q.z, q.w};
#pragma unroll
            for (int e = 0; e < 4; e++) {
                int pel = fi * 4 + e;
                int im = pel / 3072;
                int p = pel - im * 3072;
                int c = p % 3;
                int hw = p / 3;
                int w = hw & 31;
                int h = hw >> 5;
                int rec = A_OFF + (((im * 3 + c) * 8) + (w >> 4) * 2 + ((w >> 3) & 1)) * 512
                          + h * 16 + (w & 7) * 2;
                float v = vals[e];
                __bf16 hb = (__bf16)v;
                __bf16 lb = (__bf16)(v - (float)hb);
                *(__bf16*)(LDS + rec) = hb;
                *(__bf16*)(LDS + rec + 2048) = lb;
            }
        }
        if (t < 4) *(float*)(LDS + ZOFF + t * 4) = 0.f;
        __syncthreads();

        f32x16 acc0 = {0,0,0,0,0,0,0,0,0,0,0,0,0,0,0,0};
        f32x16 acc1 = acc0;

        int c = 0, d = 0, half = 0;

#define CHUNK(USE, DST, SNEXT) {                                              \
    LOADB(SNEXT, DST);                                                        \
    int rowIdx = m + d - 13;                                                  \
    bool valid = (unsigned)rowIdx < 32u;                                      \
    int a0 = A_OFF + (c * 8 + half * 2 + sub) * 512 + rowIdx * 16;            \
    int ah0o = valid ? a0 : ZOFF;                                             \
    int al0o = valid ? (a0 + 2048) : ZOFF;                                    \
    int ah1o = valid ? (a0 + 12288) : ZOFF;                                   \
    int al1o = valid ? (a0 + 14336) : ZOFF;                                   \
    FragU ah0, al0, ah1, al1;                                                 \
    ah0.f = *(const float4*)(LDS + ah0o);                                     \
    al0.f = *(const float4*)(LDS + al0o);                                     \
    ah1.f = *(const float4*)(LDS + ah1o);                                     \
    al1.f = *(const float4*)(LDS + al1o);                                     \
    acc0 = mfma16(ah0.v, USE[0].v, acc0);                                     \
    acc1 = mfma16(ah1.v, USE[0].v, acc1);                                     \
    acc0 = mfma16(ah0.v, USE[1].v, acc0);                                     \
    acc1 = mfma16(ah1.v, USE[1].v, acc1);                                     \
    acc0 = mfma16(al0.v, USE[0].v, acc0);                                     \
    acc1 = mfma16(al1.v, USE[0].v, acc1);                                     \
    half ^= 1;                                                                \
    if (!half) { d++; if (d == 27) { d = 0; c++; } }                          \
}

        for (int g = 0; g < 54; g++) {
            CHUNK(bufA, bufC, 3 * g + 2);
            CHUNK(bufB, bufA, 3 * g + 3);
            CHUNK(bufC, bufB, 3 * g + 4);
        }

        // ---- epilogue: bias + sigmoid + W_sc partial dot + reductions ----
        float b4[4];
#pragma unroll
        for (int i = 0; i < 4; i++) b4[i] = bias[i];

        float part[2][10];
#pragma unroll
        for (int i = 0; i < 2; i++)
#pragma unroll
            for (int j = 0; j < 10; j++) part[i][j] = 0.f;

        f32x16 accs[2] = {acc0, acc1};
#pragma unroll
        for (int i2 = 0; i2 < 2; i2++) {
            int ncol = wv * 32 + m;
            int wcol = ncol >> 2;
            int f = ncol & 3;
            f32x16 a = accs[i2];
#pragma unroll
            for (int r = 0; r < 16; r++) {
                int h = (r & 3) + 8 * (r >> 2) + 4 * sub;
                float v = a[r] + b4[f];
                float sg = 1.f / (1.f + expf(-v));
                const float* wr = Wsc + (size_t)((h * 32 + wcol) * 4 + f) * 10;
#pragma unroll
                for (int j = 0; j < 10; j++) part[i2][j] = fmaf(sg, wr[j], part[i2][j]);
            }
        }

#pragma unroll
        for (int off = 32; off >= 1; off >>= 1) {
#pragma unroll
            for (int i2 = 0; i2 < 2; i2++)
#pragma unroll
                for (int j = 0; j < 10; j++) part[i2][j] += __shfl_xor(part[i2][j], off, 64);
        }
        if (l == 0) {
            float* red = (float*)(LDS + SRED_OFF);
#pragma unroll
            for (int i2 = 0; i2 < 2; i2++)
#pragma unroll
                for (int j = 0; j < 10; j++) red[(wv * 2 + i2) * 10 + j] = part[i2][j];
        }
        __syncthreads();
        if (t < 20) {
            int i2 = t / 10, j = t % 10;
            const float* red = (const float*)(LDS + SRED_OFF);
            float sv = red[(0 * 2 + i2) * 10 + j] + red[(1 * 2 + i2) * 10 + j]
                     + red[(2 * 2 + i2) * 10 + j] + red[(3 * 2 + i2) * 10 + j];
            int oi = (bid * 2 + i2) * 10 + j;
            float a = td[oi];
            float tol = 1e-6f + 1e-6f * fabsf(sv);
            out[oi] = (fabsf(a - sv) <= tol) ? 1.0f : 0.0f;
        }
    }
}

extern "C" void kernel_launch(void* const* d_in, const int* in_sizes, int n_in,
                              void* d_out, int out_size, void* d_ws, size_t ws_size,
                              hipStream_t stream) {
    const float* x    = (const float*)d_in[0];
    const float* W    = (const float*)d_in[1];
    const float* U    = (const float*)d_in[2];
    const float* dw   = (const float*)d_in[3];
    const float* pw   = (const float*)d_in[4];
    const float* bias = (const float*)d_in[5];
    const float* Wtd  = (const float*)d_in[6];
    const float* Wsc  = (const float*)d_in[7];

    float* ws     = (float*)d_ws;
    float* td_acc = ws + TD_OFF;
    float* Wtdr   = ws + WTDR_OFF;
    unsigned short* Bg = (unsigned short*)((char*)d_ws + BG_BYTE_OFF);

    prep<<<241, 256, 0, stream>>>(dw, pw, Wtd, Wtdr, Bg);
    lstm_td<<<512, 256, 0, stream>>>(x, W, U, Wtdr, td_acc);
    conv_sc<<<1024, 256, 0, stream>>>(x, Bg, Wsc, bias, td_acc, (float*)d_out);
}

// Round 10
// 386.444 us; speedup vs baseline: 1.4125x; 1.4125x over previous
//
#include <hip/hip_runtime.h>
#include <math.h>

// ---------------- Workspace layout ----------------
// floats:   [0, 40960)        td accumulator (4096 x 10)
//           [40960, 81920)    Wtdr[tt][j][row][k] reordered W_td
// bytes:    [524288, +166*8192)  Bg: bf16 hi/lo B slabs in MFMA-fragment
//           order, Bg[s][plane][n][16k]; slab 8192 B; 162 real + pad slabs
#define TD_OFF 0
#define WTDR_OFF 40960
#define BG_BYTE_OFF 524288

typedef __bf16 bf16x8 __attribute__((ext_vector_type(8)));
typedef float f32x16 __attribute__((ext_vector_type(16)));

union FragU { bf16x8 v; float4 f; };

__device__ __forceinline__ f32x16 mfma16(bf16x8 a, bf16x8 b, f32x16 c) {
    return __builtin_amdgcn_mfma_f32_32x32x16_bf16(a, b, c, 0, 0, 0);
}

__device__ __forceinline__ float eluf(float v) {
    return v > 0.f ? v : __expf(v) - 1.f;
}

// ---------------- prep: Wtdr reorder + Bg build ----------------------------
// Wtdr layout [tt][j][row][k]: lanes (row) read contiguous 512 B per (tt,j).
__global__ __launch_bounds__(256) void prep(const float* __restrict__ dw,
                                            const float* __restrict__ pw,
                                            const float* __restrict__ Wtd,
                                            float* __restrict__ Wtdr,
                                            unsigned short* __restrict__ Bg) {
    int gid = blockIdx.x * 256 + threadIdx.x;
    if (gid < 40960) {
        int k = gid & 3;
        int r = gid >> 2;
        int row = r & 31; r >>= 5;
        int j = r % 10;
        int tt = r / 10;
        Wtdr[gid] = Wtd[(size_t)(row * 128 + tt * 4 + k) * 10 + j];
        return;
    }
    int g2 = gid - 40960;
    if (g2 >= 162 * 128) return;
    int n = g2 & 127;
    int s = g2 >> 7;
    int half = s & 1;
    int cd = s >> 1;
    int c = cd / 27, d = cd % 27;
    int w = n >> 2, f = n & 3;
    unsigned short* dsth = Bg + (size_t)s * 4096 + n * 16;   // ushort units
    unsigned short* dstl = dsth + 2048;
#pragma unroll
    for (int k = 0; k < 16; k++) {
        int xi = half * 16 + k;
        int dx = xi - w + 13;
        float v = 0.f;
        if (dx >= 0 && dx < 27) {
#pragma unroll
            for (int m = 0; m < 5; m++)
                v = fmaf(dw[((d * 27 + dx) * 3 + c) * 5 + m],
                         pw[(c * 5 + m) * 4 + f], v);
        }
        __bf16 h = (__bf16)v;
        __bf16 l = (__bf16)(v - (float)h);
        dsth[k] = __builtin_bit_cast(unsigned short, h);
        dstl[k] = __builtin_bit_cast(unsigned short, l);
    }
}

// ---------------- LSTM branch: R4-style (direct x loads, W/U in regs) ------
__global__ void lstm_td(const float* __restrict__ x,
                        const float* __restrict__ W,
                        const float* __restrict__ U,
                        const float* __restrict__ Wtdr,
                        float* __restrict__ td_out) {
    float rW[48], rU[64];
    const float4* W4 = (const float4*)W;
    const float4* U4 = (const float4*)U;
#pragma unroll
    for (int i = 0; i < 12; i++) {
        float4 q = W4[i];
        rW[i * 4 + 0] = q.x; rW[i * 4 + 1] = q.y;
        rW[i * 4 + 2] = q.z; rW[i * 4 + 3] = q.w;
    }
#pragma unroll
    for (int i = 0; i < 16; i++) {
        float4 q = U4[i];
        rU[i * 4 + 0] = q.x; rU[i * 4 + 1] = q.y;
        rU[i * 4 + 2] = q.z; rU[i * 4 + 3] = q.w;
    }

    int t = threadIdx.x;
    int n = blockIdx.x * 256 + t;   // n = b*32 + row
    int row = n & 31;
    const float4* xp4 = (const float4*)(x + (size_t)n * 96);

    float h0 = 0, h1 = 0, h2 = 0, h3 = 0;
    float c0 = 0, c1 = 0, c2 = 0, c3 = 0;
    float acc[10];
#pragma unroll
    for (int j = 0; j < 10; j++) acc[j] = 0.f;

    for (int g = 0; g < 8; g++) {
        float4 q0 = xp4[g * 3 + 0], q1 = xp4[g * 3 + 1], q2 = xp4[g * 3 + 2];
        float xr[12] = {q0.x, q0.y, q0.z, q0.w, q1.x, q1.y,
                        q1.z, q1.w, q2.x, q2.y, q2.z, q2.w};
#pragma unroll
        for (int st = 0; st < 4; st++) {
            int tt = g * 4 + st;
            float x0 = xr[st * 3 + 0], x1 = xr[st * 3 + 1], x2 = xr[st * 3 + 2];
            float z[16];
#pragma unroll
            for (int k = 0; k < 16; k++)
                z[k] = x0 * rW[k] + x1 * rW[16 + k] + x2 * rW[32 + k]
                     + h0 * rU[k] + h1 * rU[16 + k] + h2 * rU[32 + k] + h3 * rU[48 + k];

            float ig0 = eluf(z[0]),  ig1 = eluf(z[1]),  ig2 = eluf(z[2]),  ig3 = eluf(z[3]);
            float fg0 = eluf(z[4]),  fg1 = eluf(z[5]),  fg2 = eluf(z[6]),  fg3 = eluf(z[7]);
            float og0 = eluf(z[12]), og1 = eluf(z[13]), og2 = eluf(z[14]), og3 = eluf(z[15]);

            float zm = fmaxf(fmaxf(z[8], z[9]), fmaxf(z[10], z[11]));
            float e0 = __expf(z[8] - zm), e1 = __expf(z[9] - zm);
            float e2 = __expf(z[10] - zm), e3 = __expf(z[11] - zm);
            float inv = 1.f / (e0 + e1 + e2 + e3);
            c0 = fg0 * c0 + ig0 * (e0 * inv);
            c1 = fg1 * c1 + ig1 * (e1 * inv);
            c2 = fg2 * c2 + ig2 * (e2 * inv);
            c3 = fg3 * c3 + ig3 * (e3 * inv);

            float cm = fmaxf(fmaxf(c0, c1), fmaxf(c2, c3));
            float p0 = __expf(c0 - cm), p1 = __expf(c1 - cm);
            float p2 = __expf(c2 - cm), p3 = __expf(c3 - cm);
            float pinv = 1.f / (p0 + p1 + p2 + p3);
            h0 = og0 * (p0 * pinv); h1 = og1 * (p1 * pinv);
            h2 = og2 * (p2 * pinv); h3 = og3 * (p3 * pinv);

            // Wtdr[tt][j][row][k]: lane-contiguous float4 per (tt,j)
            const float4* wr4 = (const float4*)(Wtdr + (size_t)tt * 1280) + row;
#pragma unroll
            for (int j = 0; j < 10; j++) {
                float4 q = wr4[j * 32];
                acc[j] += h0 * q.x + h1 * q.y + h2 * q.z + h3 * q.w;
            }
        }
    }

#pragma unroll
    for (int off = 16; off >= 1; off >>= 1) {
#pragma unroll
        for (int j = 0; j < 10; j++) acc[j] += __shfl_xor(acc[j], off, 64);
    }
    int lane = t & 63;
    if (lane == 0 || lane == 32) {
        int b = n >> 5;
#pragma unroll
        for (int j = 0; j < 10; j++) td_out[b * 10 + j] = acc[j];
    }
}

// ---------------- conv branch: 4 img/block, wave = 2 img x 2 nt ------------
// LDS bytes/MFMA halved vs R8 (4 b128 A-reads feed 12 MFMAs); B-global per
// MFMA unchanged. Conflict-free A layout [img][c][oct(4hi,4lo)][row][16B].
// Depth-2 load-after-use B rotation, no in-loop barriers, fused bool epilogue.
#define A_OFF 0
#define ZOFF 49152           /* 16 B zeros */
#define SRED_OFF 49168       /* 4 waves * 2 img * 10 floats */
#define LDS_BYTES 49488

__global__ __launch_bounds__(256, 3) void conv_sc(const float* __restrict__ x,
                                                  const unsigned short* __restrict__ Bg,
                                                  const float* __restrict__ Wsc,
                                                  const float* __restrict__ bias,
                                                  const float* __restrict__ td,
                                                  float* __restrict__ out) {
    __shared__ char LDS[LDS_BYTES] __attribute__((aligned(16)));
    int t = threadIdx.x;
    int l = t & 63;
    int wv = t >> 6;
    int m = l & 31;
    int sub = l >> 5;          // k-subgroup (8 k's each)
    int img0 = (wv >> 1) * 2;  // image pair base
    int ntbase = (wv & 1) * 2; // ntile pair base

    const char* bbase = (const char*)Bg + (size_t)ntbase * 1024 + m * 32 + sub * 16;
    FragU bufA[4], bufB[4];
#define LOADB(sv, arr) { const char* p_ = bbase + (size_t)(sv) * 8192;       \
        arr[0].f = *(const float4*)(p_);         /* nt0 hi */                \
        arr[1].f = *(const float4*)(p_ + 4096);  /* nt0 lo */                \
        arr[2].f = *(const float4*)(p_ + 1024);  /* nt1 hi */                \
        arr[3].f = *(const float4*)(p_ + 5120); }/* nt1 lo */

    LOADB(0, bufA);
    LOADB(1, bufB);

    // ---- stage A: 4 images -> [img][c][oct(4hi,4lo)][row][16B] ----
    const float4* xb4 = (const float4*)(x + (size_t)blockIdx.x * 12288);
#pragma unroll
    for (int it = 0; it < 12; it++) {
        int fi = it * 256 + t;            // 3072 float4 per block
        float4 q = xb4[fi];
        float vals[4] = {q.x, q.y, q.z, q.w};
#pragma unroll
        for (int e = 0; e < 4; e++) {
            int pel = fi * 4 + e;
            int im = pel / 3072;
            int p = pel - im * 3072;
            int c = p % 3;
            int hw = p / 3;
            int w = hw & 31;
            int h = hw >> 5;
            int rec = A_OFF + im * 12288
                      + ((c * 8) + (w >> 4) * 2 + ((w >> 3) & 1)) * 512
                      + h * 16 + (w & 7) * 2;
            float v = vals[e];
            __bf16 hb = (__bf16)v;
            __bf16 lb = (__bf16)(v - (float)hb);
            *(__bf16*)(LDS + rec) = hb;
            *(__bf16*)(LDS + rec + 2048) = lb;
        }
    }
    if (t < 4) *(float*)(LDS + ZOFF + t * 4) = 0.f;
    __syncthreads();   // the only barrier before the epilogue

    f32x16 acc00 = {0,0,0,0,0,0,0,0,0,0,0,0,0,0,0,0};
    f32x16 acc01 = acc00, acc10 = acc00, acc11 = acc00;

    int c = 0, d = 0, half = 0;

#define CHUNK(USE, SNEXT) {                                                   \
    int rowIdx = m + d - 13;                                                  \
    bool valid = (unsigned)rowIdx < 32u;                                      \
    int a0 = A_OFF + img0 * 12288 + (c * 8 + half * 2 + sub) * 512 + rowIdx * 16; \
    int ah0o = valid ? a0 : ZOFF;                                             \
    int al0o = valid ? (a0 + 2048) : ZOFF;                                    \
    int ah1o = valid ? (a0 + 12288) : ZOFF;                                   \
    int al1o = valid ? (a0 + 14336) : ZOFF;                                   \
    FragU ah0, al0, ah1, al1;                                                 \
    ah0.f = *(const float4*)(LDS + ah0o);                                     \
    al0.f = *(const float4*)(LDS + al0o);                                     \
    ah1.f = *(const float4*)(LDS + ah1o);                                     \
    al1.f = *(const float4*)(LDS + al1o);                                     \
    acc00 = mfma16(ah0.v, USE[0].v, acc00);                                   \
    acc01 = mfma16(ah0.v, USE[2].v, acc01);                                   \
    acc10 = mfma16(ah1.v, USE[0].v, acc10);                                   \
    acc11 = mfma16(ah1.v, USE[2].v, acc11);                                   \
    acc00 = mfma16(ah0.v, USE[1].v, acc00);                                   \
    acc01 = mfma16(ah0.v, USE[3].v, acc01);                                   \
    acc10 = mfma16(ah1.v, USE[1].v, acc10);                                   \
    acc11 = mfma16(ah1.v, USE[3].v, acc11);                                   \
    acc00 = mfma16(al0.v, USE[0].v, acc00);                                   \
    acc01 = mfma16(al0.v, USE[2].v, acc01);                                   \
    acc10 = mfma16(al1.v, USE[0].v, acc10);                                   \
    acc11 = mfma16(al1.v, USE[2].v, acc11);                                   \
    LOADB(SNEXT, USE);                                                        \
    half ^= 1;                                                                \
    if (!half) { d++; if (d == 27) { d = 0; c++; } }                          \
}

    for (int g = 0; g < 81; g++) {
        CHUNK(bufA, 2 * g + 2);
        CHUNK(bufB, 2 * g + 3);
    }

    // ---- epilogue: bias + sigmoid + W_sc partial dot + reductions ----
    float b4[4];
#pragma unroll
    for (int i = 0; i < 4; i++) b4[i] = bias[i];

    float part[2][10];
#pragma unroll
    for (int i = 0; i < 2; i++)
#pragma unroll
        for (int j = 0; j < 10; j++) part[i][j] = 0.f;

    f32x16 accs[2][2] = {{acc00, acc01}, {acc10, acc11}};
#pragma unroll
    for (int i2 = 0; i2 < 2; i2++) {
#pragma unroll
        for (int j2 = 0; j2 < 2; j2++) {
            int ncol = (ntbase + j2) * 32 + m;
            int wcol = ncol >> 2;
            int f = ncol & 3;
            f32x16 a = accs[i2][j2];
#pragma unroll
            for (int r = 0; r < 16; r++) {
                int h = (r & 3) + 8 * (r >> 2) + 4 * sub;
                float v = a[r] + b4[f];
                float sg = 1.f / (1.f + expf(-v));
                const float* wr = Wsc + (size_t)((h * 32 + wcol) * 4 + f) * 10;
#pragma unroll
                for (int j = 0; j < 10; j++) part[i2][j] = fmaf(sg, wr[j], part[i2][j]);
            }
        }
    }

#pragma unroll
    for (int off = 32; off >= 1; off >>= 1) {
#pragma unroll
        for (int i2 = 0; i2 < 2; i2++)
#pragma unroll
            for (int j = 0; j < 10; j++) part[i2][j] += __shfl_xor(part[i2][j], off, 64);
    }
    if (l == 0) {
        float* red = (float*)(LDS + SRED_OFF);
#pragma unroll
        for (int i2 = 0; i2 < 2; i2++)
#pragma unroll
            for (int j = 0; j < 10; j++) red[(wv * 2 + i2) * 10 + j] = part[i2][j];
    }
    __syncthreads();
    if (t < 40) {
        int img = t / 10, j = t % 10;
        const float* red = (const float*)(LDS + SRED_OFF);
        int pair = img >> 1, i2 = img & 1;
        float sv = red[((pair * 2) * 2 + i2) * 10 + j]
                 + red[((pair * 2 + 1) * 2 + i2) * 10 + j];
        int oi = (blockIdx.x * 4 + img) * 10 + j;
        float a = td[oi];
        float tol = 1e-6f + 1e-6f * fabsf(sv);
        out[oi] = (fabsf(a - sv) <= tol) ? 1.0f : 0.0f;
    }
}

extern "C" void kernel_launch(void* const* d_in, const int* in_sizes, int n_in,
                              void* d_out, int out_size, void* d_ws, size_t ws_size,
                              hipStream_t stream) {
    const float* x    = (const float*)d_in[0];
    const float* W    = (const float*)d_in[1];
    const float* U    = (const float*)d_in[2];
    const float* dw   = (const float*)d_in[3];
    const float* pw   = (const float*)d_in[4];
    const float* bias = (const float*)d_in[5];
    const float* Wtd  = (const float*)d_in[6];
    const float* Wsc  = (const float*)d_in[7];

    float* ws     = (float*)d_ws;
    float* td_acc = ws + TD_OFF;
    float* Wtdr   = ws + WTDR_OFF;
    unsigned short* Bg = (unsigned short*)((char*)d_ws + BG_BYTE_OFF);

    prep<<<241, 256, 0, stream>>>(dw, pw, Wtd, Wtdr, Bg);
    lstm_td<<<512, 256, 0, stream>>>(x, W, U, Wtdr, td_acc);
    conv_sc<<<1024, 256, 0, stream>>>(x, Bg, Wsc, bias, td_acc, (float*)d_out);
}